// Round 2
// baseline (657.705 us; speedup 1.0000x reference)
//
#include <hip/hip_runtime.h>
#include <stdint.h>

#define E_NUM 8
#define H_DIM 1024
#define I_DIM 4096
#define N_TOK 2048
#define TOPK 2
#define NPAIR (N_TOK*TOPK)          // 4096
#define TM 128                       // slot padding granularity
#define MAXSLOT (NPAIR + E_NUM*TM)   // 5120
#define MAXTILE (MAXSLOT/TM)         // 40

typedef unsigned short u16;
typedef unsigned int u32;
typedef short short8 __attribute__((ext_vector_type(8)));   // 8 bf16 (4 VGPRs)
typedef float f32x4 __attribute__((ext_vector_type(4)));

// ---- workspace layout (bytes) ----
#define OFF_W1T  ((size_t)0)                  // [E][I][H] bf16 = 64 MiB
#define OFF_W3T  ((size_t)67108864)
#define OFF_W2T  ((size_t)134217728)          // [E][H][I] bf16 = 64 MiB
#define OFF_T    ((size_t)201326592)          // [MAXSLOT][I] bf16 = 40 MiB
#define OFF_Y    ((size_t)243269632)          // [MAXSLOT][H] bf16 = 10 MiB
#define OFF_XB   ((size_t)253755392)          // [N][H] bf16 = 4 MiB
#define OFF_META ((size_t)257949696)
// meta (int32 word indices):
#define M_TILES    0      // [0] = tiles_total
#define M_TEXP     8      // tile_expert[MAXTILE]
#define M_SLOTTOK  64     // slot_token[MAXSLOT]  (-1 = padding)
#define M_SLOTOF   5184   // slot_of_pair[NPAIR]
#define M_ZERO     9472   // zero page, 544 ints (covers zb+co+k0 reads)
#define M_ZERO_N   544

__device__ __forceinline__ float b2f(u16 h){ return __uint_as_float(((u32)h)<<16); }
__device__ __forceinline__ u16 f2b(float f){
  u32 u = __float_as_uint(f);
  u32 r = (u + 0x7FFFu + ((u>>16)&1u)) >> 16;   // RNE
  return (u16)r;
}
// async global->LDS, 16B per lane. LDS dest must be wave-uniform base + lane*16.
__device__ __forceinline__ void glds16(const void* g, void* l){
  __builtin_amdgcn_global_load_lds((const __attribute__((address_space(1))) void*)g,
                                   (__attribute__((address_space(3))) void*)l, 16, 0, 0);
}

// ---------------- routing: counting sort of 4096 pairs by expert ----------------
__global__ __launch_bounds__(256) void route_kernel(const int* __restrict__ ei,
                                                    int* __restrict__ meta){
  __shared__ int cnt[E_NUM], base_s[E_NUM], cur[E_NUM];
  int t = threadIdx.x;
  if (t < E_NUM) cnt[t] = 0;
  __syncthreads();
  for (int p = t; p < NPAIR; p += 256) atomicAdd(&cnt[ei[p]], 1);
  __syncthreads();
  if (t == 0){
    int run = 0, tile = 0;
    for (int e = 0; e < E_NUM; ++e){
      base_s[e] = run;
      int nt = (cnt[e] + TM - 1) / TM;
      for (int i = 0; i < nt; ++i) meta[M_TEXP + tile + i] = e;
      tile += nt;
      run  += nt * TM;
    }
    meta[M_TILES] = tile;
  }
  if (t < E_NUM) cur[t] = 0;
  for (int s = t; s < MAXSLOT; s += 256) meta[M_SLOTTOK + s] = -1;
  for (int z = t; z < M_ZERO_N; z += 256) meta[M_ZERO + z] = 0;
  __syncthreads();
  for (int p = t; p < NPAIR; p += 256){
    int e = ei[p];
    int r = atomicAdd(&cur[e], 1);
    int slot = base_s[e] + r;
    meta[M_SLOTTOK + slot] = p >> 1;     // token id
    meta[M_SLOTOF + p] = slot;
  }
}

// ---------------- x cast: fp32 [N][H] -> bf16 [N][H] ----------------
__global__ __launch_bounds__(256) void castx_kernel(const float* __restrict__ x,
                                                    u16* __restrict__ xb){
  int gid = blockIdx.x * 256 + threadIdx.x;   // one per 8 elements
  size_t base = (size_t)gid * 8;
  float4 a = *(const float4*)(x + base);
  float4 b = *(const float4*)(x + base + 4);
  u16 o[8] __attribute__((aligned(16)));
  o[0]=f2b(a.x); o[1]=f2b(a.y); o[2]=f2b(a.z); o[3]=f2b(a.w);
  o[4]=f2b(b.x); o[5]=f2b(b.y); o[6]=f2b(b.z); o[7]=f2b(b.w);
  *(uint4*)(void*)(xb + base) = *(const uint4*)(const void*)o;
}

// ---------------- weight transpose+downcast: fp32 [E][R][C] -> bf16 [E][C][R] ----------------
// per-thread 8x8 register transpose; 128x128 tile per block
__global__ __launch_bounds__(256) void transpose_kernel(const float* __restrict__ src,
                                                        u16* __restrict__ dst,
                                                        int R, int C){
  int e  = blockIdx.z;
  int rb = blockIdx.y * 128 + (threadIdx.x >> 4) * 8;
  int cb = blockIdx.x * 128 + (threadIdx.x & 15) * 8;
  const float* s = src + (size_t)e * R * C;
  u16* d = dst + (size_t)e * R * C;
  float in[8][8];
  #pragma unroll
  for (int j = 0; j < 8; ++j){
    *(float4*)(void*)&in[j][0] = *(const float4*)(const void*)(s + (size_t)(rb + j) * C + cb);
    *(float4*)(void*)&in[j][4] = *(const float4*)(const void*)(s + (size_t)(rb + j) * C + cb + 4);
  }
  #pragma unroll
  for (int j = 0; j < 8; ++j){
    u16 o[8] __attribute__((aligned(16)));
    #pragma unroll
    for (int k = 0; k < 8; ++k) o[k] = f2b(in[k][j]);
    *(uint4*)(void*)(d + (size_t)(cb + j) * R + rb) = *(const uint4*)(const void*)o;
  }
}

// ---------------- phase 1: T[slot][i] = silu(x@W1) * (x@W3), grouped ----------------
// BM=128 slots x BN=64 i-cols, BK=64, 256 thr (4 waves, 2x2), dual accumulators.
__global__ __launch_bounds__(256) void ffn1_kernel(
    const u16* __restrict__ x, const u16* __restrict__ w1t, const u16* __restrict__ w3t,
    u16* __restrict__ T, const int* __restrict__ meta)
{
  const int tiles = meta[M_TILES];
  const int mt_i = blockIdx.y;
  if (mt_i >= tiles) return;
  const int e = meta[M_TEXP + mt_i];
  const int slot0 = mt_i * 128;
  const int i0 = blockIdx.x * 64;

  __shared__ u16 sA[128*64];
  __shared__ u16 sB1[64*64];
  __shared__ u16 sB3[64*64];

  const int t = threadIdx.x;
  const int lane = t & 63;
  const int wave = t >> 6;
  const int m0 = (wave >> 1) * 64;
  const int n0 = (wave & 1) * 32;
  const int lr = lane & 15;
  const int lk = (lane >> 4) * 8;

  const u16* zb = (const u16*)(meta + M_ZERO);
  const u16* abase[4]; u16* aldst[4];
  #pragma unroll
  for (int r = 0; r < 4; ++r){
    int chunk = r*256 + t;              // 1024 chunks of 16B cover 128x64 bf16
    int row = chunk >> 3;
    int co  = (chunk & 7) * 8;
    int tok = meta[M_SLOTTOK + slot0 + row];
    abase[r] = (tok >= 0) ? (x + (size_t)tok*H_DIM + co) : (zb + co); // zero page spans k0 range
    aldst[r] = sA + chunk*8;
  }
  const u16* b1base[2]; const u16* b3base[2]; u16* b1dst[2]; u16* b3dst[2];
  #pragma unroll
  for (int r = 0; r < 2; ++r){
    int chunk = r*256 + t;              // 512 chunks cover 64x64 bf16
    int n  = chunk >> 3;
    int co = (chunk & 7) * 8;
    size_t gb = ((size_t)e*I_DIM + i0 + n)*H_DIM + co;  // w1t/w3t: [E][I][H], k-contig
    b1base[r] = w1t + gb;  b3base[r] = w3t + gb;
    b1dst[r] = sB1 + chunk*8;  b3dst[r] = sB3 + chunk*8;
  }

  f32x4 zero4 = {0.f,0.f,0.f,0.f};
  f32x4 accG[4][2], accU[4][2];
  #pragma unroll
  for (int a = 0; a < 4; ++a){
    accG[a][0]=zero4; accG[a][1]=zero4; accU[a][0]=zero4; accU[a][1]=zero4;
  }

  for (int k0 = 0; k0 < H_DIM; k0 += 64){
    #pragma unroll
    for (int r = 0; r < 4; ++r) glds16(abase[r] + k0, aldst[r]);
    #pragma unroll
    for (int r = 0; r < 2; ++r){
      glds16(b1base[r] + k0, b1dst[r]);
      glds16(b3base[r] + k0, b3dst[r]);
    }
    __syncthreads();
    #pragma unroll
    for (int ks = 0; ks < 64; ks += 32){
      short8 af[4];
      #pragma unroll
      for (int m = 0; m < 4; ++m)
        af[m] = *(const short8*)(const void*)(sA + (m0 + m*16 + lr)*64 + ks + lk);
      #pragma unroll
      for (int n = 0; n < 2; ++n){
        short8 bg = *(const short8*)(const void*)(sB1 + (n0 + n*16 + lr)*64 + ks + lk);
        short8 bu = *(const short8*)(const void*)(sB3 + (n0 + n*16 + lr)*64 + ks + lk);
        #pragma unroll
        for (int m = 0; m < 4; ++m){
          accG[m][n] = __builtin_amdgcn_mfma_f32_16x16x32_bf16(af[m], bg, accG[m][n], 0,0,0);
          accU[m][n] = __builtin_amdgcn_mfma_f32_16x16x32_bf16(af[m], bu, accU[m][n], 0,0,0);
        }
      }
    }
    __syncthreads();
  }

  // epilogue: silu(gate)*up -> bf16. C/D layout: col=lane&15, row=(lane>>4)*4+r
  #pragma unroll
  for (int m = 0; m < 4; ++m)
  #pragma unroll
  for (int n = 0; n < 2; ++n)
  #pragma unroll
  for (int r = 0; r < 4; ++r){
    int row = m0 + m*16 + (lane>>4)*4 + r;
    int col = i0 + n0 + n*16 + lr;
    float g = accG[m][n][r];
    float u = accU[m][n][r];
    float val = (g / (1.0f + __expf(-g))) * u;
    T[(size_t)(slot0 + row)*I_DIM + col] = f2b(val);
  }
}

// ---------------- phase 2: Y[slot][h] = T @ W2, grouped ----------------
__global__ __launch_bounds__(256) void ffn2_kernel(
    const u16* __restrict__ T, const u16* __restrict__ w2t,
    u16* __restrict__ Y, const int* __restrict__ meta)
{
  const int tiles = meta[M_TILES];
  const int mt_i = blockIdx.y;
  if (mt_i >= tiles) return;
  const int e = meta[M_TEXP + mt_i];
  const int slot0 = mt_i * 128;
  const int h0 = blockIdx.x * 64;

  __shared__ u16 sA[128*64];
  __shared__ u16 sB[64*64];

  const int t = threadIdx.x;
  const int lane = t & 63;
  const int wave = t >> 6;
  const int m0 = (wave >> 1) * 64;
  const int n0 = (wave & 1) * 32;
  const int lr = lane & 15;
  const int lk = (lane >> 4) * 8;

  const u16* abase[4]; u16* aldst[4];
  #pragma unroll
  for (int r = 0; r < 4; ++r){
    int chunk = r*256 + t;
    int row = chunk >> 3;
    int co  = (chunk & 7) * 8;
    abase[r] = T + (size_t)(slot0 + row)*I_DIM + co;   // pad rows of T are exact zeros
    aldst[r] = sA + chunk*8;
  }
  const u16* bbase[2]; u16* bdst[2];
  #pragma unroll
  for (int r = 0; r < 2; ++r){
    int chunk = r*256 + t;
    int n  = chunk >> 3;
    int co = (chunk & 7) * 8;
    bbase[r] = w2t + ((size_t)e*H_DIM + h0 + n)*I_DIM + co;  // w2t: [E][H][I], k-contig
    bdst[r] = sB + chunk*8;
  }

  f32x4 zero4 = {0.f,0.f,0.f,0.f};
  f32x4 acc[4][2];
  #pragma unroll
  for (int a = 0; a < 4; ++a){ acc[a][0]=zero4; acc[a][1]=zero4; }

  for (int k0 = 0; k0 < I_DIM; k0 += 64){
    #pragma unroll
    for (int r = 0; r < 4; ++r) glds16(abase[r] + k0, aldst[r]);
    #pragma unroll
    for (int r = 0; r < 2; ++r) glds16(bbase[r] + k0, bdst[r]);
    __syncthreads();
    #pragma unroll
    for (int ks = 0; ks < 64; ks += 32){
      short8 af[4];
      #pragma unroll
      for (int m = 0; m < 4; ++m)
        af[m] = *(const short8*)(const void*)(sA + (m0 + m*16 + lr)*64 + ks + lk);
      #pragma unroll
      for (int n = 0; n < 2; ++n){
        short8 bf = *(const short8*)(const void*)(sB + (n0 + n*16 + lr)*64 + ks + lk);
        #pragma unroll
        for (int m = 0; m < 4; ++m)
          acc[m][n] = __builtin_amdgcn_mfma_f32_16x16x32_bf16(af[m], bf, acc[m][n], 0,0,0);
      }
    }
    __syncthreads();
  }

  #pragma unroll
  for (int m = 0; m < 4; ++m)
  #pragma unroll
  for (int n = 0; n < 2; ++n)
  #pragma unroll
  for (int r = 0; r < 4; ++r){
    int row = m0 + m*16 + (lane>>4)*4 + r;
    int col = h0 + n0 + n*16 + lr;
    Y[(size_t)(slot0 + row)*H_DIM + col] = f2b(acc[m][n][r]);
  }
}

// ---------------- combine: out[n] = w0*Y[slot(n,0)] + w1*Y[slot(n,1)] ----------------
__global__ __launch_bounds__(256) void combine_kernel(
    const u16* __restrict__ Y, const float* __restrict__ ew,
    const int* __restrict__ meta, float* __restrict__ out)
{
  int gid = blockIdx.x * 256 + threadIdx.x;     // N*H/8 threads
  int n  = gid >> 7;
  int hc = (gid & 127) * 8;
  int s0 = meta[M_SLOTOF + n*2];
  int s1 = meta[M_SLOTOF + n*2 + 1];
  float w0 = ew[n*2];
  float w1v = ew[n*2 + 1];
  const short8 y0 = *(const short8*)(const void*)(Y + (size_t)s0*H_DIM + hc);
  const short8 y1 = *(const short8*)(const void*)(Y + (size_t)s1*H_DIM + hc);
  float o[8];
  #pragma unroll
  for (int j = 0; j < 8; ++j)
    o[j] = w0 * b2f((u16)y0[j]) + w1v * b2f((u16)y1[j]);
  float4* outv = (float4*)(out + (size_t)n*H_DIM + hc);
  outv[0] = *(float4*)(void*)&o[0];
  outv[1] = *(float4*)(void*)&o[4];
}

extern "C" void kernel_launch(void* const* d_in, const int* in_sizes, int n_in,
                              void* d_out, int out_size, void* d_ws, size_t ws_size,
                              hipStream_t stream)
{
  const float* x  = (const float*)d_in[0];
  const int*   ei = (const int*)d_in[1];
  const float* ew = (const float*)d_in[2];
  const float* w1 = (const float*)d_in[3];
  const float* w2 = (const float*)d_in[4];
  const float* w3 = (const float*)d_in[5];
  float* out = (float*)d_out;
  char* ws = (char*)d_ws;
  u16* w1t = (u16*)(ws + OFF_W1T);
  u16* w3t = (u16*)(ws + OFF_W3T);
  u16* w2t = (u16*)(ws + OFF_W2T);
  u16* Tb  = (u16*)(ws + OFF_T);
  u16* Yb  = (u16*)(ws + OFF_Y);
  u16* xb  = (u16*)(ws + OFF_XB);
  int* meta = (int*)(ws + OFF_META);

  route_kernel<<<1, 256, 0, stream>>>(ei, meta);
  castx_kernel<<<dim3((N_TOK*H_DIM/8)/256), 256, 0, stream>>>(x, xb);
  transpose_kernel<<<dim3(I_DIM/128, H_DIM/128, E_NUM), 256, 0, stream>>>(w1, w1t, H_DIM, I_DIM);
  transpose_kernel<<<dim3(I_DIM/128, H_DIM/128, E_NUM), 256, 0, stream>>>(w3, w3t, H_DIM, I_DIM);
  transpose_kernel<<<dim3(H_DIM/128, I_DIM/128, E_NUM), 256, 0, stream>>>(w2, w2t, I_DIM, H_DIM);
  ffn1_kernel<<<dim3(I_DIM/64, MAXTILE), 256, 0, stream>>>(xb, w1t, w3t, Tb, meta);
  ffn2_kernel<<<dim3(H_DIM/64, MAXTILE), 256, 0, stream>>>(Tb, w2t, Yb, meta);
  combine_kernel<<<dim3((N_TOK*H_DIM/8)/256), 256, 0, stream>>>(Yb, ew, meta, out);
}

// Round 3
// 607.700 us; speedup vs baseline: 1.0823x; 1.0823x over previous
//
#include <hip/hip_runtime.h>
#include <stdint.h>

#define E_NUM 8
#define H_DIM 1024
#define I_DIM 4096
#define N_TOK 2048
#define TOPK 2
#define NPAIR (N_TOK*TOPK)          // 4096
#define TM 128                       // slot padding granularity
#define MAXSLOT (NPAIR + E_NUM*TM)   // 5120
#define MAXTILE (MAXSLOT/TM)         // 40

typedef unsigned short u16;
typedef unsigned int u32;
typedef short short8 __attribute__((ext_vector_type(8)));   // 8 bf16 (4 VGPRs)
typedef float f32x4 __attribute__((ext_vector_type(4)));

// ---- workspace layout (bytes) ----
#define OFF_W1T  ((size_t)0)                  // [E][I][H] bf16 = 64 MiB
#define OFF_W3T  ((size_t)67108864)
#define OFF_W2T  ((size_t)134217728)          // [E][H][I] bf16 = 64 MiB
#define OFF_T    ((size_t)201326592)          // [MAXSLOT][I] bf16 = 40 MiB
#define OFF_Y    ((size_t)243269632)          // [MAXSLOT][H] bf16 = 10 MiB
#define OFF_XB   ((size_t)253755392)          // [N][H] bf16 = 4 MiB
#define OFF_META ((size_t)257949696)
// meta (int32 word indices):
#define M_TILES    0      // [0] = tiles_total
#define M_TEXP     8      // tile_expert[MAXTILE]
#define M_SLOTTOK  64     // slot_token[MAXSLOT]  (-1 = padding)
#define M_SLOTOF   5184   // slot_of_pair[NPAIR]
#define M_ZERO     9472   // zero page, 544 ints (covers zb+co+k0 reads)
#define M_ZERO_N   544

__device__ __forceinline__ float b2f(u16 h){ return __uint_as_float(((u32)h)<<16); }
__device__ __forceinline__ u16 f2b(float f){
  u32 u = __float_as_uint(f);
  u32 r = (u + 0x7FFFu + ((u>>16)&1u)) >> 16;   // RNE
  return (u16)r;
}
// async global->LDS, 16B per lane. LDS dest must be wave-uniform base + lane*16.
__device__ __forceinline__ void glds16(const void* g, void* l){
  __builtin_amdgcn_global_load_lds((const __attribute__((address_space(1))) void*)g,
                                   (__attribute__((address_space(3))) void*)l, 16, 0, 0);
}
// XOR bank swizzle: LDS chunk c (16B units, 8 chunks/row) holds global k-segment
// (c&7)^((c>>3)&7) of row c>>3. Reads of segment j, row r go to chunk r*8+(j^(r&7)).
__device__ __forceinline__ int swz_co(int chunk){   // global element offset of k-segment
  return (((chunk >> 3) ^ chunk) & 7) * 8;
}

// ---------------- routing: counting sort of 4096 pairs by expert ----------------
__global__ __launch_bounds__(256) void route_kernel(const int* __restrict__ ei,
                                                    int* __restrict__ meta){
  __shared__ int cnt[E_NUM], base_s[E_NUM], cur[E_NUM];
  int t = threadIdx.x;
  if (t < E_NUM) cnt[t] = 0;
  __syncthreads();
  for (int p = t; p < NPAIR; p += 256) atomicAdd(&cnt[ei[p]], 1);
  __syncthreads();
  if (t == 0){
    int run = 0, tile = 0;
    for (int e = 0; e < E_NUM; ++e){
      base_s[e] = run;
      int nt = (cnt[e] + TM - 1) / TM;
      for (int i = 0; i < nt; ++i) meta[M_TEXP + tile + i] = e;
      tile += nt;
      run  += nt * TM;
    }
    meta[M_TILES] = tile;
  }
  if (t < E_NUM) cur[t] = 0;
  for (int s = t; s < MAXSLOT; s += 256) meta[M_SLOTTOK + s] = -1;
  for (int z = t; z < M_ZERO_N; z += 256) meta[M_ZERO + z] = 0;
  __syncthreads();
  for (int p = t; p < NPAIR; p += 256){
    int e = ei[p];
    int r = atomicAdd(&cur[e], 1);
    int slot = base_s[e] + r;
    meta[M_SLOTTOK + slot] = p >> 1;     // token id
    meta[M_SLOTOF + p] = slot;
  }
}

// ---------------- x cast: fp32 [N][H] -> bf16 [N][H] ----------------
__global__ __launch_bounds__(256) void castx_kernel(const float* __restrict__ x,
                                                    u16* __restrict__ xb){
  int gid = blockIdx.x * 256 + threadIdx.x;   // one per 8 elements
  size_t base = (size_t)gid * 8;
  float4 a = *(const float4*)(x + base);
  float4 b = *(const float4*)(x + base + 4);
  u16 o[8] __attribute__((aligned(16)));
  o[0]=f2b(a.x); o[1]=f2b(a.y); o[2]=f2b(a.z); o[3]=f2b(a.w);
  o[4]=f2b(b.x); o[5]=f2b(b.y); o[6]=f2b(b.z); o[7]=f2b(b.w);
  *(uint4*)(void*)(xb + base) = *(const uint4*)(const void*)o;
}

// ---------------- weight transpose+downcast via LDS (coalesced both sides) ----------------
// fp32 [E][R][C] -> bf16 [E][C][R]; 128x128 tile per block, 256 threads.
// LDS pitch 129 u16 (odd) -> column reads land on distinct banks (2-way max).
__global__ __launch_bounds__(256) void transpose_kernel(const float* __restrict__ src,
                                                        u16* __restrict__ dst,
                                                        int R, int C){
  __shared__ u16 tile[128*129];
  int e  = blockIdx.z;
  int cb = blockIdx.x * 128;
  int rb = blockIdx.y * 128;
  const float* s = src + (size_t)e * R * C;
  u16* d = dst + (size_t)e * R * C;
  int tid = threadIdx.x;
  #pragma unroll
  for (int it = 0; it < 16; ++it){
    int idx = it*256 + tid;
    int row = idx >> 5, colq = (idx & 31) * 4;
    float4 v = *(const float4*)(s + (size_t)(rb+row)*C + cb + colq);
    u16* p = &tile[row*129 + colq];
    p[0]=f2b(v.x); p[1]=f2b(v.y); p[2]=f2b(v.z); p[3]=f2b(v.w);
  }
  __syncthreads();
  #pragma unroll
  for (int it = 0; it < 8; ++it){
    int idx = it*256 + tid;
    int orow = idx >> 4, oc = (idx & 15) * 8;
    u16 o[8] __attribute__((aligned(16)));
    #pragma unroll
    for (int k = 0; k < 8; ++k) o[k] = tile[(oc+k)*129 + orow];
    *(uint4*)(void*)(d + (size_t)(cb+orow)*R + rb + oc) = *(const uint4*)(const void*)o;
  }
}

// ---------------- phase 1: T[slot][i] = silu(x@W1) * (x@W3), grouped ----------------
// BM=128 slots x BN=64 i-cols, BK=64, 256 thr (4 waves, 2x2), dual accumulators.
__global__ __launch_bounds__(256) void ffn1_kernel(
    const u16* __restrict__ x, const u16* __restrict__ w1t, const u16* __restrict__ w3t,
    u16* __restrict__ T, const int* __restrict__ meta)
{
  const int tiles = meta[M_TILES];
  const int mt_i = blockIdx.y;
  if (mt_i >= tiles) return;
  const int e = meta[M_TEXP + mt_i];
  const int slot0 = mt_i * 128;
  const int i0 = blockIdx.x * 64;

  __shared__ u16 sA[128*64];
  __shared__ u16 sB1[64*64];
  __shared__ u16 sB3[64*64];

  const int t = threadIdx.x;
  const int lane = t & 63;
  const int wave = t >> 6;
  const int m0 = (wave >> 1) * 64;
  const int n0 = (wave & 1) * 32;
  const int lr = lane & 15;
  const int lq = lane >> 4;          // 0..3

  const u16* zb = (const u16*)(meta + M_ZERO);
  const u16* abase[4]; u16* aldst[4];
  #pragma unroll
  for (int r = 0; r < 4; ++r){
    int chunk = r*256 + t;              // 1024 chunks of 16B cover 128x64 bf16
    int row = chunk >> 3;
    int co  = swz_co(chunk);            // swizzled k-segment
    int tok = meta[M_SLOTTOK + slot0 + row];
    abase[r] = (tok >= 0) ? (x + (size_t)tok*H_DIM + co) : (zb + co);
    aldst[r] = sA + chunk*8;
  }
  const u16* b1base[2]; const u16* b3base[2]; u16* b1dst[2]; u16* b3dst[2];
  #pragma unroll
  for (int r = 0; r < 2; ++r){
    int chunk = r*256 + t;              // 512 chunks cover 64x64 bf16
    int n  = chunk >> 3;
    int co = swz_co(chunk);
    size_t gb = ((size_t)e*I_DIM + i0 + n)*H_DIM + co;  // w1t/w3t: [E][I][H], k-contig
    b1base[r] = w1t + gb;  b3base[r] = w3t + gb;
    b1dst[r] = sB1 + chunk*8;  b3dst[r] = sB3 + chunk*8;
  }

  f32x4 zero4 = {0.f,0.f,0.f,0.f};
  f32x4 accG[4][2], accU[4][2];
  #pragma unroll
  for (int a = 0; a < 4; ++a){
    accG[a][0]=zero4; accG[a][1]=zero4; accU[a][0]=zero4; accU[a][1]=zero4;
  }

  for (int k0 = 0; k0 < H_DIM; k0 += 64){
    #pragma unroll
    for (int r = 0; r < 4; ++r) glds16(abase[r] + k0, aldst[r]);
    #pragma unroll
    for (int r = 0; r < 2; ++r){
      glds16(b1base[r] + k0, b1dst[r]);
      glds16(b3base[r] + k0, b3dst[r]);
    }
    __syncthreads();
    #pragma unroll
    for (int ks = 0; ks < 64; ks += 32){
      // k-segment index jj = ks/8 + lq; row r has its segment jj at chunk r*8+(jj^(r&7));
      // r&7 == lr&7 for all frags -> per-lane constant xor.
      const int sx = ((ks >> 3) + lq) ^ (lr & 7);
      short8 af[4];
      #pragma unroll
      for (int m = 0; m < 4; ++m)
        af[m] = *(const short8*)(const void*)(sA + (m0 + m*16 + lr)*64 + sx*8);
      #pragma unroll
      for (int n = 0; n < 2; ++n){
        short8 bg = *(const short8*)(const void*)(sB1 + (n0 + n*16 + lr)*64 + sx*8);
        short8 bu = *(const short8*)(const void*)(sB3 + (n0 + n*16 + lr)*64 + sx*8);
        #pragma unroll
        for (int m = 0; m < 4; ++m){
          accG[m][n] = __builtin_amdgcn_mfma_f32_16x16x32_bf16(af[m], bg, accG[m][n], 0,0,0);
          accU[m][n] = __builtin_amdgcn_mfma_f32_16x16x32_bf16(af[m], bu, accU[m][n], 0,0,0);
        }
      }
    }
    __syncthreads();
  }

  // epilogue: silu(gate)*up -> bf16. C/D layout: col=lane&15, row=(lane>>4)*4+r
  #pragma unroll
  for (int m = 0; m < 4; ++m)
  #pragma unroll
  for (int n = 0; n < 2; ++n)
  #pragma unroll
  for (int r = 0; r < 4; ++r){
    int row = m0 + m*16 + lq*4 + r;
    int col = i0 + n0 + n*16 + lr;
    float g = accG[m][n][r];
    float u = accU[m][n][r];
    float val = (g / (1.0f + __expf(-g))) * u;
    T[(size_t)(slot0 + row)*I_DIM + col] = f2b(val);
  }
}

// ---------------- phase 2: Y[slot][h] = T @ W2, grouped ----------------
__global__ __launch_bounds__(256) void ffn2_kernel(
    const u16* __restrict__ T, const u16* __restrict__ w2t,
    u16* __restrict__ Y, const int* __restrict__ meta)
{
  const int tiles = meta[M_TILES];
  const int mt_i = blockIdx.y;
  if (mt_i >= tiles) return;
  const int e = meta[M_TEXP + mt_i];
  const int slot0 = mt_i * 128;
  const int h0 = blockIdx.x * 64;

  __shared__ u16 sA[128*64];
  __shared__ u16 sB[64*64];

  const int t = threadIdx.x;
  const int lane = t & 63;
  const int wave = t >> 6;
  const int m0 = (wave >> 1) * 64;
  const int n0 = (wave & 1) * 32;
  const int lr = lane & 15;
  const int lq = lane >> 4;

  const u16* abase[4]; u16* aldst[4];
  #pragma unroll
  for (int r = 0; r < 4; ++r){
    int chunk = r*256 + t;
    int row = chunk >> 3;
    int co  = swz_co(chunk);
    abase[r] = T + (size_t)(slot0 + row)*I_DIM + co;   // pad rows of T are exact zeros
    aldst[r] = sA + chunk*8;
  }
  const u16* bbase[2]; u16* bdst[2];
  #pragma unroll
  for (int r = 0; r < 2; ++r){
    int chunk = r*256 + t;
    int n  = chunk >> 3;
    int co = swz_co(chunk);
    bbase[r] = w2t + ((size_t)e*H_DIM + h0 + n)*I_DIM + co;  // w2t: [E][H][I], k-contig
    bdst[r] = sB + chunk*8;
  }

  f32x4 zero4 = {0.f,0.f,0.f,0.f};
  f32x4 acc[4][2];
  #pragma unroll
  for (int a = 0; a < 4; ++a){ acc[a][0]=zero4; acc[a][1]=zero4; }

  for (int k0 = 0; k0 < I_DIM; k0 += 64){
    #pragma unroll
    for (int r = 0; r < 4; ++r) glds16(abase[r] + k0, aldst[r]);
    #pragma unroll
    for (int r = 0; r < 2; ++r) glds16(bbase[r] + k0, bdst[r]);
    __syncthreads();
    #pragma unroll
    for (int ks = 0; ks < 64; ks += 32){
      const int sx = ((ks >> 3) + lq) ^ (lr & 7);
      short8 af[4];
      #pragma unroll
      for (int m = 0; m < 4; ++m)
        af[m] = *(const short8*)(const void*)(sA + (m0 + m*16 + lr)*64 + sx*8);
      #pragma unroll
      for (int n = 0; n < 2; ++n){
        short8 bf = *(const short8*)(const void*)(sB + (n0 + n*16 + lr)*64 + sx*8);
        #pragma unroll
        for (int m = 0; m < 4; ++m)
          acc[m][n] = __builtin_amdgcn_mfma_f32_16x16x32_bf16(af[m], bf, acc[m][n], 0,0,0);
      }
    }
    __syncthreads();
  }

  #pragma unroll
  for (int m = 0; m < 4; ++m)
  #pragma unroll
  for (int n = 0; n < 2; ++n)
  #pragma unroll
  for (int r = 0; r < 4; ++r){
    int row = m0 + m*16 + lq*4 + r;
    int col = h0 + n0 + n*16 + lr;
    Y[(size_t)(slot0 + row)*H_DIM + col] = f2b(acc[m][n][r]);
  }
}

// ---------------- combine: out[n] = w0*Y[slot(n,0)] + w1*Y[slot(n,1)] ----------------
__global__ __launch_bounds__(256) void combine_kernel(
    const u16* __restrict__ Y, const float* __restrict__ ew,
    const int* __restrict__ meta, float* __restrict__ out)
{
  int gid = blockIdx.x * 256 + threadIdx.x;     // N*H/8 threads
  int n  = gid >> 7;
  int hc = (gid & 127) * 8;
  int s0 = meta[M_SLOTOF + n*2];
  int s1 = meta[M_SLOTOF + n*2 + 1];
  float w0 = ew[n*2];
  float w1v = ew[n*2 + 1];
  const short8 y0 = *(const short8*)(const void*)(Y + (size_t)s0*H_DIM + hc);
  const short8 y1 = *(const short8*)(const void*)(Y + (size_t)s1*H_DIM + hc);
  float o[8];
  #pragma unroll
  for (int j = 0; j < 8; ++j)
    o[j] = w0 * b2f((u16)y0[j]) + w1v * b2f((u16)y1[j]);
  float4* outv = (float4*)(out + (size_t)n*H_DIM + hc);
  outv[0] = *(float4*)(void*)&o[0];
  outv[1] = *(float4*)(void*)&o[4];
}

extern "C" void kernel_launch(void* const* d_in, const int* in_sizes, int n_in,
                              void* d_out, int out_size, void* d_ws, size_t ws_size,
                              hipStream_t stream)
{
  const float* x  = (const float*)d_in[0];
  const int*   ei = (const int*)d_in[1];
  const float* ew = (const float*)d_in[2];
  const float* w1 = (const float*)d_in[3];
  const float* w2 = (const float*)d_in[4];
  const float* w3 = (const float*)d_in[5];
  float* out = (float*)d_out;
  char* ws = (char*)d_ws;
  u16* w1t = (u16*)(ws + OFF_W1T);
  u16* w3t = (u16*)(ws + OFF_W3T);
  u16* w2t = (u16*)(ws + OFF_W2T);
  u16* Tb  = (u16*)(ws + OFF_T);
  u16* Yb  = (u16*)(ws + OFF_Y);
  u16* xb  = (u16*)(ws + OFF_XB);
  int* meta = (int*)(ws + OFF_META);

  route_kernel<<<1, 256, 0, stream>>>(ei, meta);
  castx_kernel<<<dim3((N_TOK*H_DIM/8)/256), 256, 0, stream>>>(x, xb);
  transpose_kernel<<<dim3(I_DIM/128, H_DIM/128, E_NUM), 256, 0, stream>>>(w1, w1t, H_DIM, I_DIM);
  transpose_kernel<<<dim3(I_DIM/128, H_DIM/128, E_NUM), 256, 0, stream>>>(w3, w3t, H_DIM, I_DIM);
  transpose_kernel<<<dim3(H_DIM/128, I_DIM/128, E_NUM), 256, 0, stream>>>(w2, w2t, I_DIM, H_DIM);
  ffn1_kernel<<<dim3(I_DIM/64, MAXTILE), 256, 0, stream>>>(xb, w1t, w3t, Tb, meta);
  ffn2_kernel<<<dim3(H_DIM/64, MAXTILE), 256, 0, stream>>>(Tb, w2t, Yb, meta);
  combine_kernel<<<dim3((N_TOK*H_DIM/8)/256), 256, 0, stream>>>(Yb, ew, meta, out);
}